// Round 5
// baseline (956.469 us; speedup 1.0000x reference)
//
#include <hip/hip_runtime.h>
#include <hip/hip_cooperative_groups.h>
#include <stdint.h>

namespace cg = cooperative_groups;

#define NUM_NODES 1000000
#define H_DIM 64
#define OUT_DIM 32
#define NUM_RELS 64
#define NUM_BASES 4
#define N_SRC0 400000
#define N_DST1 100000
#define N_DST2 20000
#define E1 600000
#define E2 300000
#define NDST_TOT (N_DST1 + N_DST2)
#define E_TOT (E1 + E2)

typedef __attribute__((ext_vector_type(8))) short bf16x8;
typedef __attribute__((ext_vector_type(4))) float floatx4;

__device__ __forceinline__ unsigned short f2bf(float f){
  union{float f; unsigned u;} v; v.f=f;
  unsigned u=v.u;
  unsigned r=(u + 0x7FFFu + ((u>>16)&1u))>>16;
  return (unsigned short)r;
}
__device__ __forceinline__ float bf2f(unsigned short h){
  union{unsigned u; float f;} v; v.u=((unsigned)h)<<16; return v.f;
}

// ---- single cooperative kernel: deg-zero + Btab build + histogram +
// 3-phase exclusive scan + scatter. Replaces 6 dispatches (init, hist,
// scan_sum, scan_bsum, scan_final, scatter) with 1 — identical work &
// arithmetic, grid.sync() where the kernel boundaries were.
__global__ __launch_bounds__(512) void k_build(
    const float* __restrict__ V1, const float* __restrict__ V2,
    const int* __restrict__ input_nodes,
    const int* __restrict__ src1, const int* __restrict__ dst1,
    const int* __restrict__ ety1, const float* __restrict__ nrm1,
    const int* __restrict__ src2, const int* __restrict__ dst2,
    const int* __restrict__ ety2, const float* __restrict__ nrm2,
    ushort* __restrict__ Btab1, ushort* __restrict__ Btab2,
    int* __restrict__ deg, int* __restrict__ bsum, int* __restrict__ boff,
    int* __restrict__ offs, int* __restrict__ cursor,
    uint2* __restrict__ meta)
{
  cg::grid_group grid = cg::this_grid();
  const int T = gridDim.x * 512;
  const int gtid = blockIdx.x*512 + threadIdx.x;
  const int tid = threadIdx.x;
  __shared__ int lds[1024];            // [0..511] C1 scan, [512..1023] C2

  // ---- Phase A: zero deg + build B fragment tables ----
  for (int i = gtid; i < NDST_TOT; i += T) deg[i] = 0;
  for (int t = gtid; t < 24576; t += T){
    if (t < 16384){
      int j = t & 7, lane = (t>>3)&63, kk = (t>>9)&7, nt = t>>12;   // nt<4
      int kdim = kk*32 + (lane>>4)*8 + j;
      int o = nt*16 + (lane&15);
      int k = kdim>>2, b = kdim&3;
      Btab1[t] = f2bf(V1[(b*64 + k)*64 + o]);
    } else {
      int u = t - 16384;
      int j = u & 7, lane = (u>>3)&63, kk = (u>>9)&7, nt = u>>12;   // nt<2
      int kdim = kk*32 + (lane>>4)*8 + j;
      int o = nt*16 + (lane&15);
      int k = kdim>>2, b = kdim&3;
      Btab2[u] = f2bf(V2[(b*64 + k)*32 + o]);
    }
  }
  grid.sync();

  // ---- Phase B: histogram over both graphs' dst ----
  for (int e = gtid; e < E_TOT; e += T){
    if (e < E1) atomicAdd(&deg[dst1[e]], 1);
    else        atomicAdd(&deg[N_DST1 + dst2[e - E1]], 1);
  }
  grid.sync();

  // ---- Phase C1: per-block inclusive scan of 1024-elem chunks ----
  const int nb = (NDST_TOT + 1023) >> 10;      // 118
  int v0 = 0, v1 = 0;
  if ((int)blockIdx.x < nb){
    int i0 = blockIdx.x*1024 + tid*2;
    v0 = (i0   < NDST_TOT) ? deg[i0]   : 0;
    v1 = (i0+1 < NDST_TOT) ? deg[i0+1] : 0;
    int s = v0 + v1;
    lds[tid] = s; __syncthreads();
    for (int off = 1; off < 512; off <<= 1){
      int t2 = (tid >= off) ? lds[tid-off] : 0; __syncthreads();
      lds[tid] += t2; __syncthreads();
    }
    if (tid == 511) bsum[blockIdx.x] = lds[511];
  }
  grid.sync();

  // ---- Phase C2: block 0 exclusive-scans the 118 block sums ----
  if (blockIdx.x == 0){
    int v = (tid < nb) ? bsum[tid] : 0;
    lds[512 + tid] = v; __syncthreads();
    for (int off = 1; off < 512; off <<= 1){
      int t2 = (tid >= off) ? lds[512 + tid - off] : 0; __syncthreads();
      lds[512 + tid] += t2; __syncthreads();
    }
    if (tid < nb) boff[tid] = lds[512 + tid] - v;   // exclusive
  }
  grid.sync();

  // ---- Phase C3: write offs/cursor (global exclusive prefix) ----
  if ((int)blockIdx.x < nb){
    int base = boff[blockIdx.x];
    int ex = base + lds[tid] - (v0 + v1);
    int i0 = blockIdx.x*1024 + tid*2;
    if (i0   < NDST_TOT){ offs[i0]   = ex;      cursor[i0]   = ex;      }
    if (i0+1 < NDST_TOT){ offs[i0+1] = ex + v0; cursor[i0+1] = ex + v0; }
  }
  if (blockIdx.x == 0 && tid == 0) offs[NDST_TOT] = E_TOT;
  grid.sync();

  // ---- Phase D: scatter both graphs into packed 8 B dst-sorted meta ----
  for (int t = gtid; t < E_TOT; t += T){
    int d, s, et; float nv;
    if (t < E1){
      d = dst1[t]; s = input_nodes[src1[t]]; et = ety1[t]; nv = nrm1[t];
    } else {
      int e = t - E1;
      d = N_DST1 + dst2[e]; s = src2[e]; et = ety2[e]; nv = nrm2[e];
    }
    int p = atomicAdd(&cursor[d], 1);
    uint2 m; m.x = (unsigned)s | ((unsigned)et << 20);
    m.y = __float_as_uint(nv);
    meta[p] = m;
  }
}

// ---- fused aggregate + GEMM per layer (unchanged from R4) ----
__global__ __launch_bounds__(1024) void k_agg_gemm1(
    const float* __restrict__ emb, const int* __restrict__ offs,
    const uint2* __restrict__ meta, const float4* __restrict__ comp4,
    const ushort* __restrict__ Btab, const float* __restrict__ bias,
    ushort* __restrict__ h_bf){
  __shared__ ushort zt[16][264];
  int lane = threadIdx.x & 63;
  int w = threadIdx.x >> 6;            // 0..15, one dst row per wave
  int mbase = blockIdx.x * 16;
  int d = mbase + w;
  int e0 = __builtin_amdgcn_readfirstlane(offs[d]);
  int e1 = __builtin_amdgcn_readfirstlane(offs[d+1]);
  float a0=0.f, a1=0.f, a2=0.f, a3=0.f;
  for (int e = e0; e < e1; e += 8){
    int idx[8]; float msk[8];
    #pragma unroll
    for (int k=0;k<8;k++){
      int t = e + k;
      idx[k] = (t < e1) ? t : e0;
      msk[k] = (t < e1) ? 1.f : 0.f;
    }
    int s[8]; float4 c[8];
    #pragma unroll
    for (int k=0;k<8;k++){
      uint2 m = meta[idx[k]];
      unsigned pk = __builtin_amdgcn_readfirstlane(m.x);
      float nv = __uint_as_float(__builtin_amdgcn_readfirstlane(m.y));
      s[k] = (int)(pk & 0xFFFFFu);
      float4 cp = comp4[pk >> 20];
      c[k].x = cp.x*nv; c[k].y = cp.y*nv; c[k].z = cp.z*nv; c[k].w = cp.w*nv;
    }
    float x[8];
    #pragma unroll
    for (int k=0;k<8;k++)
      x[k] = emb[(size_t)s[k]*64 + lane] * msk[k];
    #pragma unroll
    for (int k=0;k<8;k++){
      a0 = fmaf(c[k].x, x[k], a0);
      a1 = fmaf(c[k].y, x[k], a1);
      a2 = fmaf(c[k].z, x[k], a2);
      a3 = fmaf(c[k].w, x[k], a3);
    }
  }
  ushort4 o; o.x=f2bf(a0); o.y=f2bf(a1); o.z=f2bf(a2); o.w=f2bf(a3);
  *(ushort4*)&zt[w][lane*4] = o;
  __syncthreads();
  if (w < 4){
    int quad = lane>>4, l15 = lane&15;
    bf16x8 a[8];
    #pragma unroll
    for (int kk=0; kk<8; kk++)
      a[kk] = *(const bf16x8*)&zt[l15][kk*32 + quad*8];
    floatx4 acc = {0.f,0.f,0.f,0.f};
    #pragma unroll
    for (int kk=0; kk<8; kk++){
      bf16x8 b = *((const bf16x8*)(Btab + ((w*8 + kk)*64 + lane)*8));
      acc = __builtin_amdgcn_mfma_f32_16x16x32_bf16(a[kk], b, acc, 0, 0, 0);
    }
    int col = w*16 + l15;
    float bv = bias[col];
    #pragma unroll
    for (int r=0; r<4; r++){
      int row = mbase + quad*4 + r;
      float v = fmaxf(acc[r] + bv, 0.f);
      h_bf[(size_t)row*64 + col] = f2bf(v);
    }
  }
}

__global__ __launch_bounds__(1024) void k_agg_gemm2(
    const ushort* __restrict__ hin, const int* __restrict__ offs,
    const uint2* __restrict__ meta, const float4* __restrict__ comp4,
    const ushort* __restrict__ Btab, const float* __restrict__ bias,
    float* __restrict__ out){
  __shared__ ushort zt[16][264];
  int lane = threadIdx.x & 63;
  int w = threadIdx.x >> 6;            // 0..15, one dst row per wave
  int mbase = blockIdx.x * 16;
  int d = mbase + w;
  int e0 = __builtin_amdgcn_readfirstlane(offs[d]);
  int e1 = __builtin_amdgcn_readfirstlane(offs[d+1]);
  float a0=0.f, a1=0.f, a2=0.f, a3=0.f;
  for (int e = e0; e < e1; e += 8){
    int idx[8]; float msk[8];
    #pragma unroll
    for (int k=0;k<8;k++){
      int t = e + k;
      idx[k] = (t < e1) ? t : e0;
      msk[k] = (t < e1) ? 1.f : 0.f;
    }
    int s[8]; float4 c[8];
    #pragma unroll
    for (int k=0;k<8;k++){
      uint2 m = meta[idx[k]];
      unsigned pk = __builtin_amdgcn_readfirstlane(m.x);
      float nv = __uint_as_float(__builtin_amdgcn_readfirstlane(m.y));
      s[k] = (int)(pk & 0xFFFFFu);
      float4 cp = comp4[pk >> 20];
      c[k].x = cp.x*nv; c[k].y = cp.y*nv; c[k].z = cp.z*nv; c[k].w = cp.w*nv;
    }
    float x[8];
    #pragma unroll
    for (int k=0;k<8;k++)
      x[k] = bf2f(hin[(size_t)s[k]*64 + lane]) * msk[k];
    #pragma unroll
    for (int k=0;k<8;k++){
      a0 = fmaf(c[k].x, x[k], a0);
      a1 = fmaf(c[k].y, x[k], a1);
      a2 = fmaf(c[k].z, x[k], a2);
      a3 = fmaf(c[k].w, x[k], a3);
    }
  }
  ushort4 o; o.x=f2bf(a0); o.y=f2bf(a1); o.z=f2bf(a2); o.w=f2bf(a3);
  *(ushort4*)&zt[w][lane*4] = o;
  __syncthreads();
  if (w < 2){                           // N=32 -> 2 n-tiles
    int quad = lane>>4, l15 = lane&15;
    bf16x8 a[8];
    #pragma unroll
    for (int kk=0; kk<8; kk++)
      a[kk] = *(const bf16x8*)&zt[l15][kk*32 + quad*8];
    floatx4 acc = {0.f,0.f,0.f,0.f};
    #pragma unroll
    for (int kk=0; kk<8; kk++){
      bf16x8 b = *((const bf16x8*)(Btab + ((w*8 + kk)*64 + lane)*8));
      acc = __builtin_amdgcn_mfma_f32_16x16x32_bf16(a[kk], b, acc, 0, 0, 0);
    }
    int col = w*16 + l15;
    float bv = bias[col];
    #pragma unroll
    for (int r=0; r<4; r++){
      int row = mbase + quad*4 + r;
      out[(size_t)row*32 + col] = acc[r] + bv;
    }
  }
}

extern "C" void kernel_launch(void* const* d_in, const int* in_sizes, int n_in,
                              void* d_out, int out_size, void* d_ws, size_t ws_size,
                              hipStream_t stream){
  const int*   input_nodes = (const int*)  d_in[0];
  const int*   src1  = (const int*)  d_in[1];
  const int*   dst1  = (const int*)  d_in[2];
  const int*   ety1  = (const int*)  d_in[3];
  const float* norm1 = (const float*)d_in[4];
  const int*   src2  = (const int*)  d_in[5];
  const int*   dst2  = (const int*)  d_in[6];
  const int*   ety2  = (const int*)  d_in[7];
  const float* norm2 = (const float*)d_in[8];
  const float* emb   = (const float*)d_in[9];
  const float* V1    = (const float*)d_in[10];
  const float* comp1 = (const float*)d_in[11];
  const float* b1    = (const float*)d_in[12];
  const float* V2    = (const float*)d_in[13];
  const float* comp2 = (const float*)d_in[14];
  const float* b2    = (const float*)d_in[15];
  float* out = (float*)d_out;

  char* p = (char*)d_ws;
  auto alloc = [&](size_t bytes)->char*{
    char* r = p; p += (bytes + 255) & ~(size_t)255; return r;
  };
  ushort* h_bf  = (ushort*)alloc((size_t)N_DST1*64*2);     // 12.8 MB
  ushort* Btab1 = (ushort*)alloc(16384*2);
  ushort* Btab2 = (ushort*)alloc(8192*2);
  int* deg  = (int*)alloc((size_t)NDST_TOT*4);
  int* cur  = (int*)alloc((size_t)NDST_TOT*4);
  int* offs = (int*)alloc((size_t)(NDST_TOT+1)*4);
  int* bsum = (int*)alloc(512*4);
  int* boff = (int*)alloc(512*4);
  uint2* meta = (uint2*)alloc((size_t)E_TOT*8);

  // cooperative grid size: co-resident blocks only (queried once).
  static int G = 0;
  if (G == 0){
    int occ = 0;
    hipOccupancyMaxActiveBlocksPerMultiprocessor(&occ, k_build, 512, 0);
    if (occ < 1) occ = 1;
    G = occ * 256;                 // 256 CUs on MI355X
    if (G > 1024) G = 1024;
    if (G < 256)  G = 256;         // >= 118 blocks needed for the scan
  }

  // 1. fused CSR build (deg zero + Btab + hist + scan + scatter)
  {
    void* args[] = {
      (void*)&V1, (void*)&V2, (void*)&input_nodes,
      (void*)&src1, (void*)&dst1, (void*)&ety1, (void*)&norm1,
      (void*)&src2, (void*)&dst2, (void*)&ety2, (void*)&norm2,
      (void*)&Btab1, (void*)&Btab2,
      (void*)&deg, (void*)&bsum, (void*)&boff,
      (void*)&offs, (void*)&cur, (void*)&meta
    };
    hipLaunchCooperativeKernel((const void*)k_build, dim3(G), dim3(512),
                               args, 0, stream);
  }
  // 2. layer 1 fused agg(direct emb)+gemm (+relu)
  k_agg_gemm1<<<N_DST1/16, 1024, 0, stream>>>(emb, offs, meta,
                                              (const float4*)comp1, Btab1, b1, h_bf);
  // 3. layer 2 fused agg+gemm -> out
  k_agg_gemm2<<<N_DST2/16, 1024, 0, stream>>>(h_bf, offs + N_DST1, meta,
                                              (const float4*)comp2, Btab2, b2, out);

  (void)in_sizes; (void)n_in; (void)out_size; (void)ws_size;
}